// Round 4
// baseline (139.126 us; speedup 1.0000x reference)
//
#include <hip/hip_runtime.h>
#include <hip/hip_fp16.h>

#define NH 12
#define BSZ 8
#define NSEQ 1024
#define EDIM 768
#define DH 64

typedef _Float16 f16;
typedef f16 half8 __attribute__((ext_vector_type(8)));
typedef f16 half4 __attribute__((ext_vector_type(4)));
typedef float f32x4 __attribute__((ext_vector_type(4)));
typedef unsigned int u32;
typedef u32 u32x2 __attribute__((ext_vector_type(2)));

static __device__ __forceinline__ void gload16(const void* g, void* l) {
    __builtin_amdgcn_global_load_lds((const __attribute__((address_space(1))) u32*)g,
                                     (__attribute__((address_space(3))) u32*)l, 16, 0, 0);
}
static __device__ __forceinline__ u32 pkrtz(float a, float b) {
    auto h = __builtin_amdgcn_cvt_pkrtz(a, b);
    return __builtin_bit_cast(u32, h);
}
#define MFMA16(a, b, c) __builtin_amdgcn_mfma_f32_16x16x32_f16((a), (b), (c), 0, 0, 0)

// ---------------- fused fp32 -> fp16 convert (x | w_qkv | w_proj) ----------------
__global__ void cvt_all_kernel(const float* __restrict__ x, const float* __restrict__ wq,
                               const float* __restrict__ wp, f16* __restrict__ dst) {
    const int NX = BSZ * NSEQ * EDIM;
    const int NWQ = 3 * EDIM * EDIM;
    int i = (blockIdx.x * blockDim.x + threadIdx.x) * 4;
    const float* s;
    int j;
    if (i < NX) { s = x; j = i; }
    else if (i < NX + NWQ) { s = wq; j = i - NX; }
    else { s = wp; j = i - NX - NWQ; }
    float4 v = *(const float4*)(s + j);
    half4 o = { (f16)v.x, (f16)v.y, (f16)v.z, (f16)v.w };
    *(half4*)(dst + i) = o;
}

// ---------------- GEMM: C[m][c] = sum_k A[m][k]*W[c][k] + bias[c] ----------------
// Fragment-order LDS staging: Lds[buf][sub][f][lane] holds the exact half8 MFMA
// fragment each lane reads -> ds_read_b128 at lane*16, conflict-free.
// sub 0/1 = A rows 0-63 / 64-127 ; sub 2/3 = B rows 0-63 / 64-127.
template<int MODE>
__global__ __launch_bounds__(256) void gemm_kernel(
    const f16* __restrict__ A, const f16* __restrict__ Wt, const float* __restrict__ bias,
    f16* __restrict__ qbuf, f16* __restrict__ kbuf, f16* __restrict__ vbuf,
    float* __restrict__ outp, const int* __restrict__ activep, int K, int NC)
{
    __shared__ __align__(16) f16 Lds[2][4][4][64][8];   // 32 KiB

    const int tid = threadIdx.x;
    const int c0 = blockIdx.x * 128;
    const int m0 = blockIdx.y * 128;
    if (MODE == 0) {
        int hb = (c0 % EDIM) >> 6;
        if (hb >= *activep) return;   // both heads masked -> qkv never read
    }
    const int lane = tid & 63;
    const int wid  = tid >> 6;
    const int wr = wid >> 1, wc = wid & 1;
    const int r16 = lane & 15, rg = lane >> 4;

    f32x4 acc[4][4];
#pragma unroll
    for (int i = 0; i < 4; ++i)
#pragma unroll
        for (int j = 0; j < 4; ++j)
            acc[i][j] = f32x4{0.f, 0.f, 0.f, 0.f};

    // this wave's staging source: wave 0/1 -> A-sub0/1, wave 2/3 -> B-sub0/1
    const f16* srcbase = (wid < 2) ? (A  + (size_t)(m0 + (wid & 1) * 64) * K)
                                   : (Wt + (size_t)(c0 + (wid & 1) * 64) * K);
    const f16* gsrc = srcbase + (size_t)r16 * K + rg * 8;
    const int nkt = K / 32;

    auto stage = [&](int buf, int kt) {
#pragma unroll
        for (int f = 0; f < 4; ++f)
            gload16(gsrc + (size_t)(f * 16) * K + kt * 32, &Lds[buf][wid][f][0][0]);
    };

    stage(0, 0);
    __syncthreads();
    int cur = 0;
    for (int kt = 0; kt < nkt; ++kt) {
        if (kt + 1 < nkt) stage(cur ^ 1, kt + 1);   // loads fly during MFMA below
        half8 af[4], bf[4];
#pragma unroll
        for (int f = 0; f < 4; ++f) {
            af[f] = *(const half8*)&Lds[cur][wr][f][lane][0];
            bf[f] = *(const half8*)&Lds[cur][2 + wc][f][lane][0];
        }
        __builtin_amdgcn_s_setprio(1);
#pragma unroll
        for (int fm = 0; fm < 4; ++fm)
#pragma unroll
            for (int fn = 0; fn < 4; ++fn)
                acc[fm][fn] = MFMA16(af[fm], bf[fn], acc[fm][fn]);
        __builtin_amdgcn_s_setprio(0);
        __syncthreads();   // drains vmcnt: next buffer ready
        cur ^= 1;
    }

    // epilogue: C/D layout col=lane&15, row=(lane>>4)*4+reg
#pragma unroll
    for (int fn = 0; fn < 4; ++fn) {
        const int c = c0 + wc * 64 + fn * 16 + r16;
        const float bv = bias[c];
#pragma unroll
        for (int fm = 0; fm < 4; ++fm) {
            const int mbase = m0 + wr * 64 + fm * 16 + rg * 4;
#pragma unroll
            for (int r = 0; r < 4; ++r) {
                const float val = acc[fm][fn][r] + bv;
                const int m = mbase + r;
                if (MODE == 1) {
                    outp[(size_t)m * EDIM + c] = val;
                } else {
                    const int s  = c / EDIM;
                    const int cc = c % EDIM;
                    const int hh = cc >> 6, d = cc & 63;
                    const int bb = m >> 10, n = m & 1023;
                    f16* dst = (s == 0) ? qbuf : ((s == 1) ? kbuf : vbuf);
                    dst[(((size_t)bb * NH + hh) * NSEQ + n) * DH + d] = (f16)val;
                }
            }
        }
    }
}

// ---------------- V transpose: vbuf [b][h][n][d] -> vtb [b][h][d][n] ----------------
__global__ __launch_bounds__(256) void vtrans_kernel(const f16* __restrict__ vbuf,
                                                     f16* __restrict__ vtb,
                                                     const int* __restrict__ activep) {
    const int b = blockIdx.z, h = blockIdx.y;
    if (h >= *activep) return;
    const int n0 = blockIdx.x * 64;
    __shared__ __align__(16) f16 T[64][72];
    const f16* src = vbuf + (((size_t)b * NH + h) * NSEQ + n0) * DH;
    f16* dst = vtb + ((size_t)b * NH + h) * DH * NSEQ;
    const int t = threadIdx.x;
    const int rn = t >> 2, rc = t & 3;
    *(half8*)&T[rn][rc * 16]     = *(const half8*)&src[(size_t)rn * DH + rc * 16];
    *(half8*)&T[rn][rc * 16 + 8] = *(const half8*)&src[(size_t)rn * DH + rc * 16 + 8];
    __syncthreads();
    const int d = t >> 2, nc = (t & 3) * 16;
    half8 o0, o1;
#pragma unroll
    for (int j = 0; j < 8; ++j) {
        o0[j] = T[nc + j][d];
        o1[j] = T[nc + 8 + j][d];
    }
    *(half8*)&dst[(size_t)d * NSEQ + n0 + nc]     = o0;
    *(half8*)&dst[(size_t)d * NSEQ + n0 + nc + 8] = o1;
}

// ---------------- flash attention: gload_lds K/V^T, swizzled LDS, P via LDS ----------------
__global__ __launch_bounds__(256) void attn_kernel(
    const f16* __restrict__ qbuf, const f16* __restrict__ kbuf, const f16* __restrict__ vtb,
    f16* __restrict__ ctx, const int* __restrict__ activep)
{
    __shared__ __align__(16) f16 Kh[2][64][64];
    __shared__ __align__(16) f16 Vh[2][64][64];   // swizzled V^T tile: row d, 64 k
    __shared__ __align__(16) f16 Ph[4][16][64];   // per-wave P, swizzled

    const int b = blockIdx.z, h = blockIdx.y;
    const int q0 = blockIdx.x * 64;
    const int tid = threadIdx.x, lane = tid & 63, wid = tid >> 6;

    if (h >= *activep) {
        const int r = tid >> 2, cp = tid & 3;
        half8 z = { (f16)0,(f16)0,(f16)0,(f16)0,(f16)0,(f16)0,(f16)0,(f16)0 };
        size_t base = ((size_t)b * NSEQ + q0 + r) * EDIM + h * DH + cp * 16;
        *(half8*)&ctx[base]     = z;
        *(half8*)&ctx[base + 8] = z;
        return;
    }

    const size_t hb = (((size_t)b * NH + h) * NSEQ) * DH;
    const f16* Q  = qbuf + hb;
    const char* Kp = (const char*)(kbuf + hb);
    const char* Vp = (const char*)(vtb + hb);   // rows d, stride NSEQ*2 bytes

    const int ql = lane & 15;
    const int g  = lane >> 4;
    const int q7 = ql & 7;

    // Q B-fragment, pre-scaled by 1/8 (exact in f16)
    half8 qb0, qb1;
    {
        const f16* qp = Q + (size_t)(q0 + wid * 16 + ql) * DH + g * 8;
        qb0 = *(const half8*)qp        * (f16)0.125f;
        qb1 = *(const half8*)(qp + 32) * (f16)0.125f;
    }

    // gload_lds staging with pre-swizzled global source (chunk ^= row&7)
    const int srow8 = lane >> 3;                 // row within 8-row group
    const int schk  = (lane & 7) ^ srow8;        // swizzled source chunk

    auto stage = [&](int buf, int kt) {
        const char* kb = Kp + (size_t)kt * 8192;            // 64 rows * 128B
#pragma unroll
        for (int i = 0; i < 2; ++i) {
            const int r = wid * 16 + i * 8 + srow8;
            gload16(kb + (size_t)r * 128 + schk * 16, &Kh[buf][wid * 16 + i * 8][0]);
            gload16(Vp + (size_t)r * (NSEQ * 2) + (size_t)kt * 128 + schk * 16,
                    &Vh[buf][wid * 16 + i * 8][0]);
        }
    };

    f32x4 oacc[4];
#pragma unroll
    for (int i = 0; i < 4; ++i) oacc[i] = f32x4{0.f, 0.f, 0.f, 0.f};
    float mr = -INFINITY, lr = 0.f;

    char* prow = (char*)&Ph[wid][ql][0];

    stage(0, 0);
    const int NT = NSEQ / 64;
    for (int kt = 0; kt < NT; ++kt) {
        const int cur = kt & 1;
        __syncthreads();                     // cur's loads landed; prev reads done
        if (kt + 1 < NT) stage(cur ^ 1, kt + 1);   // fly during compute below

        // S^T = K Q^T : st[s][r] = S^T[k=16s+4g+r][q=ql]
        f32x4 st[4];
        __builtin_amdgcn_s_setprio(1);
#pragma unroll
        for (int s = 0; s < 4; ++s) {
            f32x4 t = f32x4{0.f, 0.f, 0.f, 0.f};
            t = MFMA16(*(const half8*)((const char*)&Kh[cur][16 * s + ql][0] + ((g ^ q7) << 4)),       qb0, t);
            t = MFMA16(*(const half8*)((const char*)&Kh[cur][16 * s + ql][0] + (((4 | g) ^ q7) << 4)), qb1, t);
            st[s] = t;
        }
        __builtin_amdgcn_s_setprio(0);

        // online softmax (state replicated across lanes ql, ql+16, ql+32, ql+48)
        float pmax;
        {
            float m0v = fmaxf(fmaxf(st[0][0], st[0][1]), fmaxf(st[0][2], st[0][3]));
            float m1v = fmaxf(fmaxf(st[1][0], st[1][1]), fmaxf(st[1][2], st[1][3]));
            float m2v = fmaxf(fmaxf(st[2][0], st[2][1]), fmaxf(st[2][2], st[2][3]));
            float m3v = fmaxf(fmaxf(st[3][0], st[3][1]), fmaxf(st[3][2], st[3][3]));
            pmax = fmaxf(fmaxf(m0v, m1v), fmaxf(m2v, m3v));
        }
        pmax = fmaxf(pmax, __shfl_xor(pmax, 16));
        pmax = fmaxf(pmax, __shfl_xor(pmax, 32));
        const float mnew = fmaxf(mr, pmax);
        const float sc = __expf(mr - mnew);
        float psum = 0.f;
#pragma unroll
        for (int s = 0; s < 4; ++s)
#pragma unroll
            for (int r = 0; r < 4; ++r) {
                float p = __expf(st[s][r] - mnew);
                st[s][r] = p;
                psum += p;
            }
        psum += __shfl_xor(psum, 16);
        psum += __shfl_xor(psum, 32);
        lr = lr * sc + psum;
        mr = mnew;

        // rescale O accumulator (C rows are q = 4g + r)
#pragma unroll
        for (int r = 0; r < 4; ++r) {
            const float scr = __shfl(sc, (g << 2) | r);
            oacc[0][r] *= scr; oacc[1][r] *= scr; oacc[2][r] *= scr; oacc[3][r] *= scr;
        }

        // P -> per-wave swizzled LDS: row ql, halves k = 16s+4g .. +3
#pragma unroll
        for (int s = 0; s < 4; ++s) {
            u32x2 w = { pkrtz(st[s][0], st[s][1]), pkrtz(st[s][2], st[s][3]) };
            *(u32x2*)(prow + ((32 * s + 8 * g) ^ (q7 << 4))) = w;
        }
        const half8 pa0 = *(const half8*)(prow + ((16 * g) ^ (q7 << 4)));
        const half8 pa1 = *(const half8*)(prow + ((64 + 16 * g) ^ (q7 << 4)));

        // O += P V : B-frag from Vh[d][k] (swizzled)
        __builtin_amdgcn_s_setprio(1);
#pragma unroll
        for (int db = 0; db < 4; ++db) {
            oacc[db] = MFMA16(pa0, *(const half8*)((const char*)&Vh[cur][16 * db + ql][0] + ((g ^ q7) << 4)),       oacc[db]);
            oacc[db] = MFMA16(pa1, *(const half8*)((const char*)&Vh[cur][16 * db + ql][0] + (((4 | g) ^ q7) << 4)), oacc[db]);
        }
        __builtin_amdgcn_s_setprio(0);
    }

    // epilogue: rows q = 4g + r, cols d = db*16 + ql
#pragma unroll
    for (int r = 0; r < 4; ++r) {
        const float li = 1.0f / __shfl(lr, (g << 2) | r);
        const int n = q0 + wid * 16 + (g << 2) + r;
#pragma unroll
        for (int db = 0; db < 4; ++db)
            ctx[((size_t)b * NSEQ + n) * EDIM + h * DH + db * 16 + ql] = (f16)(oacc[db][r] * li);
    }
}

// ---------------- launch ----------------
extern "C" void kernel_launch(void* const* d_in, const int* in_sizes, int n_in,
                              void* d_out, int out_size, void* d_ws, size_t ws_size,
                              hipStream_t stream) {
    const float* x      = (const float*)d_in[0];
    const float* w_qkv  = (const float*)d_in[1];
    const float* b_qkv  = (const float*)d_in[2];
    const float* w_proj = (const float*)d_in[3];
    const float* b_proj = (const float*)d_in[4];
    const int*   active = (const int*)d_in[5];
    float* out = (float*)d_out;

    char* ws = (char*)d_ws;
    const size_t n_x  = (size_t)BSZ * NSEQ * EDIM;       // 6291456
    const size_t n_wq = (size_t)3 * EDIM * EDIM;         // 1769472
    const size_t n_wp = (size_t)EDIM * EDIM;             // 589824
    const size_t n_hd = (size_t)BSZ * NH * NSEQ * DH;    // 6291456 per q/k/v

    f16* xh   = (f16*)ws;
    f16* wqh  = xh + n_x;
    f16* wph  = wqh + n_wq;
    f16* qh   = wph + n_wp;
    f16* kh   = qh + n_hd;
    f16* vh   = kh + n_hd;
    f16* ctxh = vh + n_hd;
    f16* vtb  = xh;   // alias: xh is dead after gemm<0>; n_x == n_hd

    const size_t n_cvt = n_x + n_wq + n_wp;
    cvt_all_kernel<<<(int)(n_cvt / 4 / 256), 256, 0, stream>>>(x, w_qkv, w_proj, xh);

    gemm_kernel<0><<<dim3(3 * EDIM / 128, BSZ * NSEQ / 128), 256, 0, stream>>>(
        xh, wqh, b_qkv, qh, kh, vh, nullptr, active, EDIM, 3 * EDIM);

    vtrans_kernel<<<dim3(NSEQ / 64, NH, BSZ), 256, 0, stream>>>(vh, vtb, active);

    attn_kernel<<<dim3(NSEQ / 64, NH, BSZ), 256, 0, stream>>>(qh, kh, vtb, ctxh, active);

    gemm_kernel<1><<<dim3(EDIM / 128, BSZ * NSEQ / 128), 256, 0, stream>>>(
        ctxh, wph, b_proj, nullptr, nullptr, nullptr, out, active, EDIM, EDIM);
}

// Round 5
// 135.648 us; speedup vs baseline: 1.0256x; 1.0256x over previous
//
#include <hip/hip_runtime.h>
#include <hip/hip_fp16.h>

#define NH 12
#define BSZ 8
#define NSEQ 1024
#define EDIM 768
#define DH 64

typedef _Float16 f16;
typedef f16 half8 __attribute__((ext_vector_type(8)));
typedef f16 half4 __attribute__((ext_vector_type(4)));
typedef float f32x4 __attribute__((ext_vector_type(4)));
typedef unsigned int u32;
typedef u32 u32x2 __attribute__((ext_vector_type(2)));

static __device__ __forceinline__ void gload16(const void* g, void* l) {
    __builtin_amdgcn_global_load_lds((const __attribute__((address_space(1))) u32*)g,
                                     (__attribute__((address_space(3))) u32*)l, 16, 0, 0);
}
static __device__ __forceinline__ u32 pkrtz(float a, float b) {
    auto h = __builtin_amdgcn_cvt_pkrtz(a, b);
    return __builtin_bit_cast(u32, h);
}
#define MFMA16(a, b, c) __builtin_amdgcn_mfma_f32_16x16x32_f16((a), (b), (c), 0, 0, 0)

// ---------------- fused fp32 -> fp16 convert (x | w_qkv | w_proj) ----------------
__global__ void cvt_all_kernel(const float* __restrict__ x, const float* __restrict__ wq,
                               const float* __restrict__ wp, f16* __restrict__ dst) {
    const int NX = BSZ * NSEQ * EDIM;
    const int NWQ = 3 * EDIM * EDIM;
    int i = (blockIdx.x * blockDim.x + threadIdx.x) * 4;
    const float* s;
    int j;
    if (i < NX) { s = x; j = i; }
    else if (i < NX + NWQ) { s = wq; j = i - NX; }
    else { s = wp; j = i - NX - NWQ; }
    float4 v = *(const float4*)(s + j);
    half4 o = { (f16)v.x, (f16)v.y, (f16)v.z, (f16)v.w };
    *(half4*)(dst + i) = o;
}

// ---------------- GEMM: C[m][c] = sum_k A[m][k]*W[c][k] + bias[c] ----------------
// Fragment-order LDS (conflict-free ds_read_b128) + counted-vmcnt pipeline:
// 4 LDS buffers, stage(kt+2) in flight across barriers, s_waitcnt vmcnt(8)
// retires only tile kt. Raw s_barrier (NOT __syncthreads -> no vmcnt(0) drain).
template<int MODE>
__global__ __launch_bounds__(256) void gemm_kernel(
    const f16* __restrict__ A, const f16* __restrict__ Wt, const float* __restrict__ bias,
    f16* __restrict__ qbuf, f16* __restrict__ kbuf, f16* __restrict__ vbuf,
    float* __restrict__ outp, const int* __restrict__ activep, int K, int NC)
{
    __shared__ __align__(16) f16 Lds[4][4][4][64][8];   // 64 KiB: [buf][sub][f][lane][8]

    const int tid = threadIdx.x;
    const int c0 = blockIdx.x * 128;
    const int m0 = blockIdx.y * 128;
    if (MODE == 0) {
        int hb = (c0 % EDIM) >> 6;
        if (hb >= *activep) return;   // both heads masked -> qkv never read
    }
    const int lane = tid & 63;
    const int wid  = tid >> 6;
    const int wr = wid >> 1, wc = wid & 1;
    const int r16 = lane & 15, rg = lane >> 4;

    f32x4 acc[4][4];
#pragma unroll
    for (int i = 0; i < 4; ++i)
#pragma unroll
        for (int j = 0; j < 4; ++j)
            acc[i][j] = f32x4{0.f, 0.f, 0.f, 0.f};

    // this wave's staging source: wave 0/1 -> A rows 0-63/64-127, wave 2/3 -> B rows
    const f16* srcbase = (wid < 2) ? (A  + (size_t)(m0 + (wid & 1) * 64) * K)
                                   : (Wt + (size_t)(c0 + (wid & 1) * 64) * K);
    const f16* gsrc = srcbase + (size_t)r16 * K + rg * 8;
    const int nkt = K / 32;

    auto stage = [&](int buf, int kt) {
#pragma unroll
        for (int f = 0; f < 4; ++f)
            gload16(gsrc + (size_t)(f * 16) * K + kt * 32, &Lds[buf][wid][f][0][0]);
    };

    stage(0, 0);
    if (nkt > 1) stage(1, 1);
#pragma unroll 1
    for (int kt = 0; kt < nkt; ++kt) {
        if (kt + 2 < nkt) {
            stage((kt + 2) & 3, kt + 2);
            asm volatile("s_waitcnt vmcnt(8)" ::: "memory");   // tile kt landed; kt+1,kt+2 in flight
        } else if (kt + 1 < nkt) {
            asm volatile("s_waitcnt vmcnt(4)" ::: "memory");
        } else {
            asm volatile("s_waitcnt vmcnt(0)" ::: "memory");
        }
        __builtin_amdgcn_s_barrier();
        __builtin_amdgcn_sched_barrier(0);
        const int cur = kt & 3;
        half8 af[4], bf[4];
#pragma unroll
        for (int f = 0; f < 4; ++f) {
            af[f] = *(const half8*)&Lds[cur][wr][f][lane][0];
            bf[f] = *(const half8*)&Lds[cur][2 + wc][f][lane][0];
        }
        __builtin_amdgcn_s_setprio(1);
#pragma unroll
        for (int fm = 0; fm < 4; ++fm)
#pragma unroll
            for (int fn = 0; fn < 4; ++fn)
                acc[fm][fn] = MFMA16(af[fm], bf[fn], acc[fm][fn]);
        __builtin_amdgcn_s_setprio(0);
    }

    // epilogue: C/D layout col=lane&15, row=(lane>>4)*4+reg
#pragma unroll
    for (int fn = 0; fn < 4; ++fn) {
        const int c = c0 + wc * 64 + fn * 16 + r16;
        const float bv = bias[c];
#pragma unroll
        for (int fm = 0; fm < 4; ++fm) {
            const int mbase = m0 + wr * 64 + fm * 16 + rg * 4;
#pragma unroll
            for (int r = 0; r < 4; ++r) {
                const float val = acc[fm][fn][r] + bv;
                const int m = mbase + r;
                if (MODE == 1) {
                    outp[(size_t)m * EDIM + c] = val;
                } else {
                    const int s  = c / EDIM;
                    const int cc = c % EDIM;
                    const int hh = cc >> 6, d = cc & 63;
                    const int bb = m >> 10, n = m & 1023;
                    f16* dst = (s == 0) ? qbuf : ((s == 1) ? kbuf : vbuf);
                    dst[(((size_t)bb * NH + hh) * NSEQ + n) * DH + d] = (f16)val;
                }
            }
        }
    }
}

// ---------------- V transpose: vbuf [b][h][n][d] -> vtb [b][h][d][n] ----------------
__global__ __launch_bounds__(256) void vtrans_kernel(const f16* __restrict__ vbuf,
                                                     f16* __restrict__ vtb,
                                                     const int* __restrict__ activep) {
    const int b = blockIdx.z, h = blockIdx.y;
    if (h >= *activep) return;
    const int n0 = blockIdx.x * 64;
    __shared__ __align__(16) f16 T[64][72];
    const f16* src = vbuf + (((size_t)b * NH + h) * NSEQ + n0) * DH;
    f16* dst = vtb + ((size_t)b * NH + h) * DH * NSEQ;
    const int t = threadIdx.x;
    const int rn = t >> 2, rc = t & 3;
    *(half8*)&T[rn][rc * 16]     = *(const half8*)&src[(size_t)rn * DH + rc * 16];
    *(half8*)&T[rn][rc * 16 + 8] = *(const half8*)&src[(size_t)rn * DH + rc * 16 + 8];
    __syncthreads();
    const int d = t >> 2, nc = (t & 3) * 16;
    half8 o0, o1;
#pragma unroll
    for (int j = 0; j < 8; ++j) {
        o0[j] = T[nc + j][d];
        o1[j] = T[nc + 8 + j][d];
    }
    *(half8*)&dst[(size_t)d * NSEQ + n0 + nc]     = o0;
    *(half8*)&dst[(size_t)d * NSEQ + n0 + nc + 8] = o1;
}

// ---------------- flash attention: gload_lds K/V^T, swizzled LDS, P via LDS ----------------
__global__ __launch_bounds__(256) void attn_kernel(
    const f16* __restrict__ qbuf, const f16* __restrict__ kbuf, const f16* __restrict__ vtb,
    f16* __restrict__ ctx, const int* __restrict__ activep)
{
    __shared__ __align__(16) f16 Kh[2][64][64];
    __shared__ __align__(16) f16 Vh[2][64][64];   // swizzled V^T tile: row d, 64 k
    __shared__ __align__(16) f16 Ph[4][16][64];   // per-wave P, swizzled

    const int b = blockIdx.z, h = blockIdx.y;
    const int q0 = blockIdx.x * 64;
    const int tid = threadIdx.x, lane = tid & 63, wid = tid >> 6;

    if (h >= *activep) {
        const int r = tid >> 2, cp = tid & 3;
        half8 z = { (f16)0,(f16)0,(f16)0,(f16)0,(f16)0,(f16)0,(f16)0,(f16)0 };
        size_t base = ((size_t)b * NSEQ + q0 + r) * EDIM + h * DH + cp * 16;
        *(half8*)&ctx[base]     = z;
        *(half8*)&ctx[base + 8] = z;
        return;
    }

    const size_t hb = (((size_t)b * NH + h) * NSEQ) * DH;
    const f16* Q  = qbuf + hb;
    const char* Kp = (const char*)(kbuf + hb);
    const char* Vp = (const char*)(vtb + hb);   // rows d, stride NSEQ*2 bytes

    const int ql = lane & 15;
    const int g  = lane >> 4;
    const int q7 = ql & 7;

    // Q B-fragment, pre-scaled by 1/8 (exact in f16)
    half8 qb0, qb1;
    {
        const f16* qp = Q + (size_t)(q0 + wid * 16 + ql) * DH + g * 8;
        qb0 = *(const half8*)qp        * (f16)0.125f;
        qb1 = *(const half8*)(qp + 32) * (f16)0.125f;
    }

    // gload_lds staging with pre-swizzled global source (chunk ^= row&7)
    const int srow8 = lane >> 3;                 // row within 8-row group
    const int schk  = (lane & 7) ^ srow8;        // swizzled source chunk

    auto stage = [&](int buf, int kt) {
        const char* kb = Kp + (size_t)kt * 8192;            // 64 rows * 128B
#pragma unroll
        for (int i = 0; i < 2; ++i) {
            const int r = wid * 16 + i * 8 + srow8;
            gload16(kb + (size_t)r * 128 + schk * 16, &Kh[buf][wid * 16 + i * 8][0]);
            gload16(Vp + (size_t)r * (NSEQ * 2) + (size_t)kt * 128 + schk * 16,
                    &Vh[buf][wid * 16 + i * 8][0]);
        }
    };

    f32x4 oacc[4];
#pragma unroll
    for (int i = 0; i < 4; ++i) oacc[i] = f32x4{0.f, 0.f, 0.f, 0.f};
    float mr = -INFINITY, lr = 0.f;

    char* prow = (char*)&Ph[wid][ql][0];

    stage(0, 0);
    const int NT = NSEQ / 64;
    for (int kt = 0; kt < NT; ++kt) {
        const int cur = kt & 1;
        __syncthreads();                     // cur's loads landed; prev reads done
        if (kt + 1 < NT) stage(cur ^ 1, kt + 1);   // fly during compute below

        // S^T = K Q^T : st[s][r] = S^T[k=16s+4g+r][q=ql]
        f32x4 st[4];
        __builtin_amdgcn_s_setprio(1);
#pragma unroll
        for (int s = 0; s < 4; ++s) {
            f32x4 t = f32x4{0.f, 0.f, 0.f, 0.f};
            t = MFMA16(*(const half8*)((const char*)&Kh[cur][16 * s + ql][0] + ((g ^ q7) << 4)),       qb0, t);
            t = MFMA16(*(const half8*)((const char*)&Kh[cur][16 * s + ql][0] + (((4 | g) ^ q7) << 4)), qb1, t);
            st[s] = t;
        }
        __builtin_amdgcn_s_setprio(0);

        // online softmax (state replicated across lanes ql, ql+16, ql+32, ql+48)
        float pmax;
        {
            float m0v = fmaxf(fmaxf(st[0][0], st[0][1]), fmaxf(st[0][2], st[0][3]));
            float m1v = fmaxf(fmaxf(st[1][0], st[1][1]), fmaxf(st[1][2], st[1][3]));
            float m2v = fmaxf(fmaxf(st[2][0], st[2][1]), fmaxf(st[2][2], st[2][3]));
            float m3v = fmaxf(fmaxf(st[3][0], st[3][1]), fmaxf(st[3][2], st[3][3]));
            pmax = fmaxf(fmaxf(m0v, m1v), fmaxf(m2v, m3v));
        }
        pmax = fmaxf(pmax, __shfl_xor(pmax, 16));
        pmax = fmaxf(pmax, __shfl_xor(pmax, 32));
        const float mnew = fmaxf(mr, pmax);
        const float sc = __expf(mr - mnew);
        float psum = 0.f;
#pragma unroll
        for (int s = 0; s < 4; ++s)
#pragma unroll
            for (int r = 0; r < 4; ++r) {
                float p = __expf(st[s][r] - mnew);
                st[s][r] = p;
                psum += p;
            }
        psum += __shfl_xor(psum, 16);
        psum += __shfl_xor(psum, 32);
        lr = lr * sc + psum;
        mr = mnew;

        // rescale O accumulator (C rows are q = 4g + r)
#pragma unroll
        for (int r = 0; r < 4; ++r) {
            const float scr = __shfl(sc, (g << 2) | r);
            oacc[0][r] *= scr; oacc[1][r] *= scr; oacc[2][r] *= scr; oacc[3][r] *= scr;
        }

        // P -> per-wave swizzled LDS: row ql, halves k = 16s+4g .. +3
#pragma unroll
        for (int s = 0; s < 4; ++s) {
            u32x2 w = { pkrtz(st[s][0], st[s][1]), pkrtz(st[s][2], st[s][3]) };
            *(u32x2*)(prow + ((32 * s + 8 * g) ^ (q7 << 4))) = w;
        }
        const half8 pa0 = *(const half8*)(prow + ((16 * g) ^ (q7 << 4)));
        const half8 pa1 = *(const half8*)(prow + ((64 + 16 * g) ^ (q7 << 4)));

        // O += P V : B-frag from Vh[d][k] (swizzled)
        __builtin_amdgcn_s_setprio(1);
#pragma unroll
        for (int db = 0; db < 4; ++db) {
            oacc[db] = MFMA16(pa0, *(const half8*)((const char*)&Vh[cur][16 * db + ql][0] + ((g ^ q7) << 4)),       oacc[db]);
            oacc[db] = MFMA16(pa1, *(const half8*)((const char*)&Vh[cur][16 * db + ql][0] + (((4 | g) ^ q7) << 4)), oacc[db]);
        }
        __builtin_amdgcn_s_setprio(0);
    }

    // epilogue: rows q = 4g + r, cols d = db*16 + ql
#pragma unroll
    for (int r = 0; r < 4; ++r) {
        const float li = 1.0f / __shfl(lr, (g << 2) | r);
        const int n = q0 + wid * 16 + (g << 2) + r;
#pragma unroll
        for (int db = 0; db < 4; ++db)
            ctx[((size_t)b * NSEQ + n) * EDIM + h * DH + db * 16 + ql] = (f16)(oacc[db][r] * li);
    }
}

// ---------------- launch ----------------
extern "C" void kernel_launch(void* const* d_in, const int* in_sizes, int n_in,
                              void* d_out, int out_size, void* d_ws, size_t ws_size,
                              hipStream_t stream) {
    const float* x      = (const float*)d_in[0];
    const float* w_qkv  = (const float*)d_in[1];
    const float* b_qkv  = (const float*)d_in[2];
    const float* w_proj = (const float*)d_in[3];
    const float* b_proj = (const float*)d_in[4];
    const int*   active = (const int*)d_in[5];
    float* out = (float*)d_out;

    char* ws = (char*)d_ws;
    const size_t n_x  = (size_t)BSZ * NSEQ * EDIM;       // 6291456
    const size_t n_wq = (size_t)3 * EDIM * EDIM;         // 1769472
    const size_t n_wp = (size_t)EDIM * EDIM;             // 589824
    const size_t n_hd = (size_t)BSZ * NH * NSEQ * DH;    // 6291456 per q/k/v

    f16* xh   = (f16*)ws;
    f16* wqh  = xh + n_x;
    f16* wph  = wqh + n_wq;
    f16* qh   = wph + n_wp;
    f16* kh   = qh + n_hd;
    f16* vh   = kh + n_hd;
    f16* ctxh = vh + n_hd;
    f16* vtb  = xh;   // alias: xh is dead after gemm<0>; n_x == n_hd

    const size_t n_cvt = n_x + n_wq + n_wp;
    cvt_all_kernel<<<(int)(n_cvt / 4 / 256), 256, 0, stream>>>(x, w_qkv, w_proj, xh);

    gemm_kernel<0><<<dim3(3 * EDIM / 128, BSZ * NSEQ / 128), 256, 0, stream>>>(
        xh, wqh, b_qkv, qh, kh, vh, nullptr, active, EDIM, 3 * EDIM);

    vtrans_kernel<<<dim3(NSEQ / 64, NH, BSZ), 256, 0, stream>>>(vh, vtb, active);

    attn_kernel<<<dim3(NSEQ / 64, NH, BSZ), 256, 0, stream>>>(qh, kh, vtb, ctxh, active);

    gemm_kernel<1><<<dim3(EDIM / 128, BSZ * NSEQ / 128), 256, 0, stream>>>(
        ctxh, wph, b_proj, nullptr, nullptr, nullptr, out, active, EDIM, EDIM);
}

// Round 6
// 124.860 us; speedup vs baseline: 1.1143x; 1.0864x over previous
//
#include <hip/hip_runtime.h>
#include <hip/hip_fp16.h>

#define NH 12
#define BSZ 8
#define NSEQ 1024
#define EDIM 768
#define DH 64

typedef _Float16 f16;
typedef f16 half8 __attribute__((ext_vector_type(8)));
typedef f16 half4 __attribute__((ext_vector_type(4)));
typedef float f32x4 __attribute__((ext_vector_type(4)));
typedef unsigned int u32;
typedef u32 u32x2 __attribute__((ext_vector_type(2)));

static __device__ __forceinline__ void gload16(const void* g, void* l) {
    __builtin_amdgcn_global_load_lds((const __attribute__((address_space(1))) u32*)g,
                                     (__attribute__((address_space(3))) u32*)l, 16, 0, 0);
}
static __device__ __forceinline__ u32 pkrtz(float a, float b) {
    auto h = __builtin_amdgcn_cvt_pkrtz(a, b);
    return __builtin_bit_cast(u32, h);
}
#define MFMA16(a, b, c) __builtin_amdgcn_mfma_f32_16x16x32_f16((a), (b), (c), 0, 0, 0)

// ---------------- fused fp32 -> fp16 convert (x | w_qkv | w_proj) ----------------
__global__ void cvt_all_kernel(const float* __restrict__ x, const float* __restrict__ wq,
                               const float* __restrict__ wp, f16* __restrict__ dst) {
    const int NX = BSZ * NSEQ * EDIM;
    const int NWQ = 3 * EDIM * EDIM;
    int i = (blockIdx.x * blockDim.x + threadIdx.x) * 4;
    const float* s;
    int j;
    if (i < NX) { s = x; j = i; }
    else if (i < NX + NWQ) { s = wq; j = i - NX; }
    else { s = wp; j = i - NX - NWQ; }
    float4 v = *(const float4*)(s + j);
    half4 o = { (f16)v.x, (f16)v.y, (f16)v.z, (f16)v.w };
    *(half4*)(dst + i) = o;
}

// ---------------- GEMM: C[m][c] = sum_k A[m][k]*W[c][k] + bias[c] ----------------
// 128(M)x64(N)x32(K) tile, 4 waves (wave = 64x32, acc 4x2), 2-buffer gload_lds,
// XOR chunk-swizzle via pre-swizzled GLOBAL source (linear LDS dest, rule-21).
template<int MODE>
__global__ __launch_bounds__(256) void gemm_kernel(
    const f16* __restrict__ A, const f16* __restrict__ Wt, const float* __restrict__ bias,
    f16* __restrict__ qbuf, f16* __restrict__ kbuf, f16* __restrict__ vbuf,
    float* __restrict__ outp, const int* __restrict__ activep, int K, int NC)
{
    __shared__ __align__(16) f16 Ah[2][128][32];   // 16 KiB
    __shared__ __align__(16) f16 Bh[2][64][32];    //  8 KiB

    const int tid = threadIdx.x;
    const int c0 = blockIdx.x * 64;
    const int m0 = blockIdx.y * 128;
    if (MODE == 0) {
        int hb = (c0 % EDIM) >> 6;       // exactly one head per 64-col block
        if (hb >= *activep) return;      // masked head -> q/k/v never read
    }
    const int lane = tid & 63;
    const int wid  = tid >> 6;
    const int wr = wid >> 1, wc = wid & 1;
    const int r16 = lane & 15, rg = lane >> 4;

    f32x4 acc[4][2];
#pragma unroll
    for (int i = 0; i < 4; ++i)
#pragma unroll
        for (int j = 0; j < 2; ++j)
            acc[i][j] = f32x4{0.f, 0.f, 0.f, 0.f};

    // staging: row-within-16 = lane>>2; swizzled 16B chunk (within 64B row) = (lane&3)^key
    const int srow4  = lane >> 2;
    const int skey   = ((lane >> 2) & 3) ^ ((lane >> 4) & 3);
    const int schunk = (lane & 3) ^ skey;
    const f16* gA = A  + (size_t)(m0 + wid * 32 + srow4) * K + schunk * 8;
    const f16* gB = Wt + (size_t)(c0 + wid * 16 + srow4) * K + schunk * 8;
    const int nkt = K / 32;

    auto stage = [&](int buf, int kt) {
        gload16(gA + kt * 32,                  &Ah[buf][wid * 32][0]);
        gload16(gA + (size_t)16 * K + kt * 32, &Ah[buf][wid * 32 + 16][0]);
        gload16(gB + kt * 32,                  &Bh[buf][wid * 16][0]);
    };

    stage(0, 0);
    __syncthreads();
    int cur = 0;
    const int rkey = ((r16 & 3) ^ ((r16 >> 2) & 3)) << 4;   // byte offset XOR for reads
    for (int kt = 0; kt < nkt; ++kt) {
        if (kt + 1 < nkt) stage(cur ^ 1, kt + 1);   // loads fly during MFMA below
        half8 af[4], bf[2];
#pragma unroll
        for (int f = 0; f < 4; ++f)
            af[f] = *(const half8*)((const char*)&Ah[cur][wr * 64 + f * 16 + r16][0] + ((rg << 4) ^ rkey));
#pragma unroll
        for (int f = 0; f < 2; ++f)
            bf[f] = *(const half8*)((const char*)&Bh[cur][wc * 32 + f * 16 + r16][0] + ((rg << 4) ^ rkey));
#pragma unroll
        for (int fm = 0; fm < 4; ++fm)
#pragma unroll
            for (int fn = 0; fn < 2; ++fn)
                acc[fm][fn] = MFMA16(af[fm], bf[fn], acc[fm][fn]);
        __syncthreads();   // drains vmcnt: next buffer ready
        cur ^= 1;
    }

    // epilogue: C/D layout col=lane&15, row=(lane>>4)*4+reg
#pragma unroll
    for (int fn = 0; fn < 2; ++fn) {
        const int c = c0 + wc * 32 + fn * 16 + r16;
        const float bv = bias[c];
#pragma unroll
        for (int fm = 0; fm < 4; ++fm) {
            const int mbase = m0 + wr * 64 + fm * 16 + rg * 4;
#pragma unroll
            for (int r = 0; r < 4; ++r) {
                const float val = acc[fm][fn][r] + bv;
                const int m = mbase + r;
                if (MODE == 1) {
                    outp[(size_t)m * EDIM + c] = val;
                } else {
                    const int s  = c / EDIM;
                    const int cc = c % EDIM;
                    const int hh = cc >> 6, d = cc & 63;
                    const int bb = m >> 10, n = m & 1023;
                    f16* dst = (s == 0) ? qbuf : ((s == 1) ? kbuf : vbuf);
                    dst[(((size_t)bb * NH + hh) * NSEQ + n) * DH + d] = (f16)val;
                }
            }
        }
    }
}

// ---------------- V transpose: vbuf [b][h][n][d] -> vtb [b][h][d][n] ----------------
__global__ __launch_bounds__(256) void vtrans_kernel(const f16* __restrict__ vbuf,
                                                     f16* __restrict__ vtb,
                                                     const int* __restrict__ activep) {
    const int b = blockIdx.z, h = blockIdx.y;
    if (h >= *activep) return;
    const int n0 = blockIdx.x * 64;
    __shared__ __align__(16) f16 T[64][72];
    const f16* src = vbuf + (((size_t)b * NH + h) * NSEQ + n0) * DH;
    f16* dst = vtb + ((size_t)b * NH + h) * DH * NSEQ;
    const int t = threadIdx.x;
    const int rn = t >> 2, rc = t & 3;
    *(half8*)&T[rn][rc * 16]     = *(const half8*)&src[(size_t)rn * DH + rc * 16];
    *(half8*)&T[rn][rc * 16 + 8] = *(const half8*)&src[(size_t)rn * DH + rc * 16 + 8];
    __syncthreads();
    const int d = t >> 2, nc = (t & 3) * 16;
    half8 o0, o1;
#pragma unroll
    for (int j = 0; j < 8; ++j) {
        o0[j] = T[nc + j][d];
        o1[j] = T[nc + 8 + j][d];
    }
    *(half8*)&dst[(size_t)d * NSEQ + n0 + nc]     = o0;
    *(half8*)&dst[(size_t)d * NSEQ + n0 + nc + 8] = o1;
}

// ---------------- flash attention: gload_lds K/V^T, swizzled LDS, P via LDS ----------------
__global__ __launch_bounds__(256) void attn_kernel(
    const f16* __restrict__ qbuf, const f16* __restrict__ kbuf, const f16* __restrict__ vtb,
    f16* __restrict__ ctx, const int* __restrict__ activep)
{
    __shared__ __align__(16) f16 Kh[2][64][64];
    __shared__ __align__(16) f16 Vh[2][64][64];   // swizzled V^T tile: row d, 64 k
    __shared__ __align__(16) f16 Ph[4][16][64];   // per-wave P, swizzled

    const int b = blockIdx.z, h = blockIdx.y;
    const int q0 = blockIdx.x * 64;
    const int tid = threadIdx.x, lane = tid & 63, wid = tid >> 6;

    if (h >= *activep) {
        const int r = tid >> 2, cp = tid & 3;
        half8 z = { (f16)0,(f16)0,(f16)0,(f16)0,(f16)0,(f16)0,(f16)0,(f16)0 };
        size_t base = ((size_t)b * NSEQ + q0 + r) * EDIM + h * DH + cp * 16;
        *(half8*)&ctx[base]     = z;
        *(half8*)&ctx[base + 8] = z;
        return;
    }

    const size_t hb = (((size_t)b * NH + h) * NSEQ) * DH;
    const f16* Q  = qbuf + hb;
    const char* Kp = (const char*)(kbuf + hb);
    const char* Vp = (const char*)(vtb + hb);   // rows d, stride NSEQ*2 bytes

    const int ql = lane & 15;
    const int g  = lane >> 4;
    const int q7 = ql & 7;

    // Q B-fragment, pre-scaled by 1/8 (exact in f16)
    half8 qb0, qb1;
    {
        const f16* qp = Q + (size_t)(q0 + wid * 16 + ql) * DH + g * 8;
        qb0 = *(const half8*)qp        * (f16)0.125f;
        qb1 = *(const half8*)(qp + 32) * (f16)0.125f;
    }

    // gload_lds staging with pre-swizzled global source (chunk ^= row&7)
    const int srow8 = lane >> 3;                 // row within 8-row group
    const int schk  = (lane & 7) ^ srow8;        // swizzled source chunk

    auto stage = [&](int buf, int kt) {
        const char* kb = Kp + (size_t)kt * 8192;            // 64 rows * 128B
#pragma unroll
        for (int i = 0; i < 2; ++i) {
            const int r = wid * 16 + i * 8 + srow8;
            gload16(kb + (size_t)r * 128 + schk * 16, &Kh[buf][wid * 16 + i * 8][0]);
            gload16(Vp + (size_t)r * (NSEQ * 2) + (size_t)kt * 128 + schk * 16,
                    &Vh[buf][wid * 16 + i * 8][0]);
        }
    };

    f32x4 oacc[4];
#pragma unroll
    for (int i = 0; i < 4; ++i) oacc[i] = f32x4{0.f, 0.f, 0.f, 0.f};
    float mr = -INFINITY, lr = 0.f;

    char* prow = (char*)&Ph[wid][ql][0];

    stage(0, 0);
    const int NT = NSEQ / 64;
    for (int kt = 0; kt < NT; ++kt) {
        const int cur = kt & 1;
        __syncthreads();                     // cur's loads landed; prev reads done
        if (kt + 1 < NT) stage(cur ^ 1, kt + 1);   // fly during compute below

        // S^T = K Q^T : st[s][r] = S^T[k=16s+4g+r][q=ql]
        f32x4 st[4];
        __builtin_amdgcn_s_setprio(1);
#pragma unroll
        for (int s = 0; s < 4; ++s) {
            f32x4 t = f32x4{0.f, 0.f, 0.f, 0.f};
            t = MFMA16(*(const half8*)((const char*)&Kh[cur][16 * s + ql][0] + ((g ^ q7) << 4)),       qb0, t);
            t = MFMA16(*(const half8*)((const char*)&Kh[cur][16 * s + ql][0] + (((4 | g) ^ q7) << 4)), qb1, t);
            st[s] = t;
        }
        __builtin_amdgcn_s_setprio(0);

        // online softmax (state replicated across lanes ql, ql+16, ql+32, ql+48)
        float pmax;
        {
            float m0v = fmaxf(fmaxf(st[0][0], st[0][1]), fmaxf(st[0][2], st[0][3]));
            float m1v = fmaxf(fmaxf(st[1][0], st[1][1]), fmaxf(st[1][2], st[1][3]));
            float m2v = fmaxf(fmaxf(st[2][0], st[2][1]), fmaxf(st[2][2], st[2][3]));
            float m3v = fmaxf(fmaxf(st[3][0], st[3][1]), fmaxf(st[3][2], st[3][3]));
            pmax = fmaxf(fmaxf(m0v, m1v), fmaxf(m2v, m3v));
        }
        pmax = fmaxf(pmax, __shfl_xor(pmax, 16));
        pmax = fmaxf(pmax, __shfl_xor(pmax, 32));
        const float mnew = fmaxf(mr, pmax);
        const float sc = __expf(mr - mnew);
        float psum = 0.f;
#pragma unroll
        for (int s = 0; s < 4; ++s)
#pragma unroll
            for (int r = 0; r < 4; ++r) {
                float p = __expf(st[s][r] - mnew);
                st[s][r] = p;
                psum += p;
            }
        psum += __shfl_xor(psum, 16);
        psum += __shfl_xor(psum, 32);
        lr = lr * sc + psum;
        mr = mnew;

        // rescale O accumulator (C rows are q = 4g + r)
#pragma unroll
        for (int r = 0; r < 4; ++r) {
            const float scr = __shfl(sc, (g << 2) | r);
            oacc[0][r] *= scr; oacc[1][r] *= scr; oacc[2][r] *= scr; oacc[3][r] *= scr;
        }

        // P -> per-wave swizzled LDS: row ql, halves k = 16s+4g .. +3
#pragma unroll
        for (int s = 0; s < 4; ++s) {
            u32x2 w = { pkrtz(st[s][0], st[s][1]), pkrtz(st[s][2], st[s][3]) };
            *(u32x2*)(prow + ((32 * s + 8 * g) ^ (q7 << 4))) = w;
        }
        const half8 pa0 = *(const half8*)(prow + ((16 * g) ^ (q7 << 4)));
        const half8 pa1 = *(const half8*)(prow + ((64 + 16 * g) ^ (q7 << 4)));

        // O += P V : B-frag from Vh[d][k] (swizzled)
        __builtin_amdgcn_s_setprio(1);
#pragma unroll
        for (int db = 0; db < 4; ++db) {
            oacc[db] = MFMA16(pa0, *(const half8*)((const char*)&Vh[cur][16 * db + ql][0] + ((g ^ q7) << 4)),       oacc[db]);
            oacc[db] = MFMA16(pa1, *(const half8*)((const char*)&Vh[cur][16 * db + ql][0] + (((4 | g) ^ q7) << 4)), oacc[db]);
        }
        __builtin_amdgcn_s_setprio(0);
    }

    // epilogue: rows q = 4g + r, cols d = db*16 + ql
#pragma unroll
    for (int r = 0; r < 4; ++r) {
        const float li = 1.0f / __shfl(lr, (g << 2) | r);
        const int n = q0 + wid * 16 + (g << 2) + r;
#pragma unroll
        for (int db = 0; db < 4; ++db)
            ctx[((size_t)b * NSEQ + n) * EDIM + h * DH + db * 16 + ql] = (f16)(oacc[db][r] * li);
    }
}

// ---------------- launch ----------------
extern "C" void kernel_launch(void* const* d_in, const int* in_sizes, int n_in,
                              void* d_out, int out_size, void* d_ws, size_t ws_size,
                              hipStream_t stream) {
    const float* x      = (const float*)d_in[0];
    const float* w_qkv  = (const float*)d_in[1];
    const float* b_qkv  = (const float*)d_in[2];
    const float* w_proj = (const float*)d_in[3];
    const float* b_proj = (const float*)d_in[4];
    const int*   active = (const int*)d_in[5];
    float* out = (float*)d_out;

    char* ws = (char*)d_ws;
    const size_t n_x  = (size_t)BSZ * NSEQ * EDIM;       // 6291456
    const size_t n_wq = (size_t)3 * EDIM * EDIM;         // 1769472
    const size_t n_wp = (size_t)EDIM * EDIM;             // 589824
    const size_t n_hd = (size_t)BSZ * NH * NSEQ * DH;    // 6291456 per q/k/v

    f16* xh   = (f16*)ws;
    f16* wqh  = xh + n_x;
    f16* wph  = wqh + n_wq;
    f16* qh   = wph + n_wp;
    f16* kh   = qh + n_hd;
    f16* vh   = kh + n_hd;
    f16* ctxh = vh + n_hd;
    f16* vtb  = xh;   // alias: xh is dead after gemm<0>; n_x == n_hd

    const size_t n_cvt = n_x + n_wq + n_wp;
    cvt_all_kernel<<<(int)(n_cvt / 4 / 256), 256, 0, stream>>>(x, w_qkv, w_proj, xh);

    gemm_kernel<0><<<dim3(3 * EDIM / 64, BSZ * NSEQ / 128), 256, 0, stream>>>(
        xh, wqh, b_qkv, qh, kh, vh, nullptr, active, EDIM, 3 * EDIM);

    vtrans_kernel<<<dim3(NSEQ / 64, NH, BSZ), 256, 0, stream>>>(vh, vtb, active);

    attn_kernel<<<dim3(NSEQ / 64, NH, BSZ), 256, 0, stream>>>(qh, kh, vtb, ctxh, active);

    gemm_kernel<1><<<dim3(EDIM / 64, BSZ * NSEQ / 128), 256, 0, stream>>>(
        ctxh, wph, b_proj, nullptr, nullptr, nullptr, out, active, EDIM, EDIM);
}